// Round 7
// baseline (124.524 us; speedup 1.0000x reference)
//
#include <hip/hip_runtime.h>
#include <math.h>

#define N_NODES 100000
#define N_EDGES 600000
#define IN_CH 128
#define HID 64
#define NEG_SLOPE 0.01f
#define NP_GRID 1024

typedef float4 f4;
typedef unsigned short u16;
typedef unsigned int u32;
typedef __attribute__((ext_vector_type(8))) short bf16x8;   // 8 bf16 (4 VGPRs)
typedef __attribute__((ext_vector_type(4))) float f32x4;    // MFMA acc

__device__ __forceinline__ float lrelu(float x) {
    return fmaxf(x, NEG_SLOPE * x);
}
__device__ __forceinline__ float uasf(u32 w) { return __uint_as_float(w); }

// HW packed conversion: one VALU op for 2 f32 -> packed bf16.
__device__ __forceinline__ u32 cvt_pk(float lo, float hi) {
    u32 r;
    asm("v_cvt_pk_bf16_f32 %0, %1, %2" : "=v"(r) : "v"(lo), "v"(hi));
    return r;
}

__device__ __forceinline__ int load_idx(const void* ei, int is64, int pos) {
    if (is64) return (int)((const long long*)ei)[pos];
    return ((const int*)ei)[pos];
}

// shared edge dot: 8 bf16 pairs vs W2 chunk
__device__ __forceinline__ float edot(uint4 a, uint4 b, f4 w0, f4 w1) {
    float s;
    s  = lrelu(uasf(a.x << 16) + uasf(b.x << 16)) * w0.x;
    s += lrelu(uasf(a.x & 0xffff0000u) + uasf(b.x & 0xffff0000u)) * w0.y;
    s += lrelu(uasf(a.y << 16) + uasf(b.y << 16)) * w0.z;
    s += lrelu(uasf(a.y & 0xffff0000u) + uasf(b.y & 0xffff0000u)) * w0.w;
    s += lrelu(uasf(a.z << 16) + uasf(b.z << 16)) * w1.x;
    s += lrelu(uasf(a.z & 0xffff0000u) + uasf(b.z & 0xffff0000u)) * w1.y;
    s += lrelu(uasf(a.w << 16) + uasf(b.w << 16)) * w1.z;
    s += lrelu(uasf(a.w & 0xffff0000u) + uasf(b.w & 0xffff0000u)) * w1.w;
    return s;
}

// ---------------------------------------------------------------------------
// Node projection v2 (round-6 structure, unchanged math) + MEASUREMENT rep
// loop: `reps` is a runtime arg (=4); each rep recomputes and rewrites the
// identical pcomb (idempotent, deterministic). Purpose: make this dispatch
// ~4x longer so it rises into the rocprof top-5 and we finally get per-phase
// counters (round 3-6 inference kept mispredicting; fills at ~40us mask both
// kernels).
// ---------------------------------------------------------------------------
__global__ __launch_bounds__(256) void node_proj_v2(
    const float* __restrict__ z, const float* __restrict__ W1l,
    const float* __restrict__ b1l, const float* __restrict__ W1r,
    const float* __restrict__ b1r, const u32* __restrict__ ei_words,
    int* __restrict__ flag, u16* __restrict__ pcomb, int reps) {
    __shared__ uint4 zt[64 * 16];   // 16 KB
    __shared__ u32 red;

    const int tid = threadIdx.x;

    if (blockIdx.x == 0) {  // is64 detect: high words of first 2048 entries
        if (tid == 0) red = 0u;
        __syncthreads();
        u32 acc = 0u;
        #pragma unroll
        for (int i = 0; i < 8; ++i)
            acc |= ei_words[(i * 256 + tid) * 2 + 1];
        atomicOr(&red, acc);
        __syncthreads();
        if (tid == 0) *flag = (red == 0u) ? 1 : 0;
    }

    const int wave = tid >> 6, lane = tid & 63;
    const int m = lane & 15, g = lane >> 4;

    // ---- W fragments -> registers (once per block)
    bf16x8 wf[2][4];
    #pragma unroll
    for (int c2 = 0; c2 < 2; ++c2) {
        const int R = (wave << 5) + (c2 << 4) + m;   // R & 15 == m
        const float* wsrc = (R < 64) ? (W1l + R * IN_CH)
                                     : (W1r + (R - 64) * IN_CH);
        #pragma unroll
        for (int kk = 0; kk < 4; ++kk) {
            const int gran = (kk << 2) | g;
            f4 a = ((const f4*)wsrc)[gran * 2];
            f4 b = ((const f4*)wsrc)[gran * 2 + 1];
            uint4 p;
            p.x = cvt_pk(a.x, a.y); p.y = cvt_pk(a.z, a.w);
            p.z = cvt_pk(b.x, b.y); p.w = cvt_pk(b.z, b.w);
            wf[c2][kk] = *(const bf16x8*)&p;
        }
    }

    const int colbase = wave << 5;
    f4 bb[2];
    #pragma unroll
    for (int c2 = 0; c2 < 2; ++c2) {
        const int col0 = colbase + (c2 << 4) + (g << 2);
        bb[c2] = *(const f4*)((colbase < 64) ? (b1l + col0) : (b1r + col0 - 64));
    }

    const int ntiles = (N_NODES + 63) / 64;  // 1563
    for (int rep = 0; rep < reps; ++rep) {
    for (int tile = blockIdx.x; tile < ntiles; tile += NP_GRID) {
        const int base = tile * 64;
        __syncthreads();   // previous tile's readers done -> zt reusable
        #pragma unroll
        for (int i = 0; i < 4; ++i) {
            int gidx = tid + i * 256;
            int row = gidx >> 4, gr = gidx & 15;
            int node = base + row;
            if (node >= N_NODES) node = N_NODES - 1;  // pad reads
            f4 a = ((const f4*)z)[node * 32 + gr * 2];
            f4 b = ((const f4*)z)[node * 32 + gr * 2 + 1];
            uint4 p;
            p.x = cvt_pk(a.x, a.y); p.y = cvt_pk(a.z, a.w);
            p.z = cvt_pk(b.x, b.y); p.w = cvt_pk(b.z, b.w);
            zt[(row << 4) | (gr ^ (row & 15))] = p;
        }
        __syncthreads();

        f32x4 acc[4][2];
        #pragma unroll
        for (int n4 = 0; n4 < 4; ++n4)
            #pragma unroll
            for (int c2 = 0; c2 < 2; ++c2) acc[n4][c2] = {0.f, 0.f, 0.f, 0.f};

        #pragma unroll
        for (int kk = 0; kk < 4; ++kk) {
            const int gran = (kk << 2) | g;
            bf16x8 zf[4];
            #pragma unroll
            for (int n4 = 0; n4 < 4; ++n4)
                zf[n4] = *(const bf16x8*)&zt[(((n4 << 4) | m) << 4) | (gran ^ m)];
            #pragma unroll
            for (int n4 = 0; n4 < 4; ++n4)
                #pragma unroll
                for (int c2 = 0; c2 < 2; ++c2)
                    acc[n4][c2] = __builtin_amdgcn_mfma_f32_16x16x32_bf16(
                        wf[c2][kk], zf[n4], acc[n4][c2], 0, 0, 0);
        }

        #pragma unroll
        for (int c2 = 0; c2 < 2; ++c2) {
            const int col0 = colbase + (c2 << 4) + (g << 2);
            #pragma unroll
            for (int n4 = 0; n4 < 4; ++n4) {
                int node = base + (n4 << 4) + m;
                if (node < N_NODES) {
                    uint2 v;
                    v.x = cvt_pk(acc[n4][c2][0] + bb[c2].x,
                                 acc[n4][c2][1] + bb[c2].y);
                    v.y = cvt_pk(acc[n4][c2][2] + bb[c2].z,
                                 acc[n4][c2][3] + bb[c2].w);
                    *(uint2*)(pcomb + (size_t)node * 128 + col0) = v;
                }
            }
        }
    }
    }
}

// ---------------------------------------------------------------------------
// Edge kernel (round-4 structure) + MEASUREMENT rep loop (same rationale).
// ---------------------------------------------------------------------------
__global__ __launch_bounds__(256) void edge_quad_kernel(
    const void* __restrict__ ei, const int* __restrict__ flag,
    const u16* __restrict__ pcomb, const float* __restrict__ W2,
    const float* __restrict__ b2, float* __restrict__ out, int reps) {
    int t = blockIdx.x * 256 + threadIdx.x;
    int q = t >> 3;
    int c = t & 7;
    if (q >= N_EDGES / 4) return;
    const int is64 = *flag;
    for (int rep = 0; rep < reps; ++rep) {
        int s[4], d[4];
        if (is64) {
            const longlong2* p = (const longlong2*)ei;
            longlong2 p0 = p[2 * q], p1 = p[2 * q + 1];
            longlong2 q0 = p[N_EDGES / 2 + 2 * q], q1 = p[N_EDGES / 2 + 2 * q + 1];
            s[0] = (int)p0.x; s[1] = (int)p0.y; s[2] = (int)p1.x; s[3] = (int)p1.y;
            d[0] = (int)q0.x; d[1] = (int)q0.y; d[2] = (int)q1.x; d[3] = (int)q1.y;
        } else {
            int4 sp = ((const int4*)ei)[q];
            int4 dp = ((const int4*)ei)[N_EDGES / 4 + q];
            s[0] = sp.x; s[1] = sp.y; s[2] = sp.z; s[3] = sp.w;
            d[0] = dp.x; d[1] = dp.y; d[2] = dp.z; d[3] = dp.w;
        }
        const uint4* pc4 = (const uint4*)pcomb;
        uint4 a0 = pc4[s[0] * 16 + c],     a1 = pc4[s[1] * 16 + c];
        uint4 a2 = pc4[s[2] * 16 + c],     a3 = pc4[s[3] * 16 + c];
        uint4 e0 = pc4[d[0] * 16 + 8 + c], e1 = pc4[d[1] * 16 + 8 + c];
        uint4 e2 = pc4[d[2] * 16 + 8 + c], e3 = pc4[d[3] * 16 + 8 + c];
        f4 w0 = ((const f4*)W2)[c * 2];
        f4 w1 = ((const f4*)W2)[c * 2 + 1];
        float r0 = edot(a0, e0, w0, w1);
        float r1 = edot(a1, e1, w0, w1);
        float r2 = edot(a2, e2, w0, w1);
        float r3 = edot(a3, e3, w0, w1);
        #pragma unroll
        for (int off = 4; off; off >>= 1) {
            r0 += __shfl_xor(r0, off, 8);
            r1 += __shfl_xor(r1, off, 8);
            r2 += __shfl_xor(r2, off, 8);
            r3 += __shfl_xor(r3, off, 8);
        }
        if (c == 0) {
            float bbs = b2[0];
            f4 o;
            o.x = 1.f / (1.f + __expf(-(r0 + bbs)));
            o.y = 1.f / (1.f + __expf(-(r1 + bbs)));
            o.z = 1.f / (1.f + __expf(-(r2 + bbs)));
            o.w = 1.f / (1.f + __expf(-(r3 + bbs)));
            *(f4*)(out + q * 4) = o;
        }
    }
}

// ---------------------------------------------------------------------------
// Tiny-workspace fallbacks (proven)
// ---------------------------------------------------------------------------
__global__ void detect_idx_kernel(const u32* __restrict__ ei_words,
                                  int* __restrict__ flag) {
    __shared__ u32 red;
    if (threadIdx.x == 0) red = 0u;
    __syncthreads();
    u32 acc = 0u;
    #pragma unroll
    for (int i = 0; i < 8; ++i)
        acc |= ei_words[(i * 256 + threadIdx.x) * 2 + 1];
    atomicOr(&red, acc);
    __syncthreads();
    if (threadIdx.x == 0) *flag = (red == 0u) ? 1 : 0;
}

__global__ __launch_bounds__(256) void edge_fallback_kernel(
    const float* __restrict__ z, const void* __restrict__ ei,
    const int* __restrict__ flag, const float* __restrict__ W1l,
    const float* __restrict__ b1l, const float* __restrict__ W1r,
    const float* __restrict__ b1r, const float* __restrict__ W2,
    const float* __restrict__ b2, float* __restrict__ out) {
    __shared__ f4 Wl4[64 * 32];
    __shared__ f4 Wr4[64 * 32];
    const int tid = threadIdx.x;
    #pragma unroll
    for (int i = 0; i < 8; ++i) {
        int gg = tid + i * 256;
        int h = gg >> 5, v = gg & 31;
        int slot = (h << 5) | (v ^ (h & 7));
        Wl4[slot] = ((const f4*)W1l)[gg];
        Wr4[slot] = ((const f4*)W1r)[gg];
    }
    __syncthreads();
    const int wave = tid >> 6, lane = tid & 63;
    int e = blockIdx.x * 4 + wave;
    if (e >= N_EDGES) return;
    const int is64 = (flag != nullptr) ? *flag : 0;
    int src = load_idx(ei, is64, e);
    int dst = load_idx(ei, is64, N_EDGES + e);
    float accl = 0.f, accr = 0.f;
    #pragma unroll 4
    for (int v = 0; v < 32; ++v) {
        f4 wl = Wl4[(lane << 5) | (v ^ (lane & 7))];
        f4 wr = Wr4[(lane << 5) | (v ^ (lane & 7))];
        f4 zl = ((const f4*)z)[src * 32 + v];
        f4 zr = ((const f4*)z)[dst * 32 + v];
        accl += wl.x * zl.x + wl.y * zl.y + wl.z * zl.z + wl.w * zl.w;
        accr += wr.x * zr.x + wr.y * zr.y + wr.z * zr.z + wr.w * zr.w;
    }
    float h = lrelu(accl + b1l[lane] + accr + b1r[lane]) * W2[lane];
    #pragma unroll
    for (int off = 32; off; off >>= 1) h += __shfl_xor(h, off, 64);
    if (lane == 0) out[e] = 1.f / (1.f + __expf(-(h + b2[0])));
}

extern "C" void kernel_launch(void* const* d_in, const int* in_sizes, int n_in,
                              void* d_out, int out_size, void* d_ws,
                              size_t ws_size, hipStream_t stream) {
    const float* z   = (const float*)d_in[0];
    const void*  ei  = d_in[1];
    const float* W1l = (const float*)d_in[2];
    const float* b1l = (const float*)d_in[3];
    const float* W1r = (const float*)d_in[4];
    const float* b1r = (const float*)d_in[5];
    const float* W2  = (const float*)d_in[6];
    const float* b2  = (const float*)d_in[7];
    float* out = (float*)d_out;

    const size_t pcomb_bytes = (size_t)N_NODES * 128 * sizeof(u16);  // 25.6 MB
    const size_t need = pcomb_bytes + 256;

    // MEASUREMENT ROUND: reps=4 on both phases (idempotent rewrites) so each
    // dispatch exceeds the ~40us fill dispatches and shows up in rocprof
    // top-5 with full counters. True per-phase time = dispatch_dur / 4.
    const int REPS = 4;

    if (ws_size >= need) {
        u16* pcomb = (u16*)d_ws;
        int* flag = (int*)((char*)d_ws + pcomb_bytes);
        node_proj_v2<<<NP_GRID, 256, 0, stream>>>(
            z, W1l, b1l, W1r, b1r, (const u32*)ei, flag, pcomb, REPS);
        edge_quad_kernel<<<(N_EDGES / 4 * 8 + 255) / 256, 256, 0, stream>>>(
            ei, flag, pcomb, W2, b2, out, REPS);
    } else if (ws_size >= 256) {
        int* flag = (int*)d_ws;
        detect_idx_kernel<<<1, 256, 0, stream>>>((const u32*)ei, flag);
        edge_fallback_kernel<<<(N_EDGES + 3) / 4, 256, 0, stream>>>(
            z, ei, flag, W1l, b1l, W1r, b1r, W2, b2, out);
    } else {
        edge_fallback_kernel<<<(N_EDGES + 3) / 4, 256, 0, stream>>>(
            z, ei, nullptr, W1l, b1l, W1r, b1r, W2, b2, out);
    }
}

// Round 9
// 54.872 us; speedup vs baseline: 2.2693x; 2.2693x over previous
//
#include <hip/hip_runtime.h>
#include <math.h>

#define N_NODES 100000
#define N_EDGES 600000
#define IN_CH 128
#define HID 64
#define NP_GRID 1024

typedef float4 f4;
typedef unsigned short u16;
typedef unsigned int u32;
typedef __attribute__((ext_vector_type(8))) short bf16x8;   // 8 bf16 (4 VGPRs)
typedef __attribute__((ext_vector_type(4))) float f32x4;    // MFMA acc
typedef __attribute__((ext_vector_type(4))) float fv4;      // native vec (nt ld)
typedef __attribute__((ext_vector_type(2))) _Float16 h2;    // packed f16
typedef __attribute__((ext_vector_type(2))) long long ll2;
typedef __attribute__((ext_vector_type(4))) int iv4;

__device__ __forceinline__ float uasf(u32 w) { return __uint_as_float(w); }

// one-VALU-op conversions
__device__ __forceinline__ u32 cvt_pk_bf(float lo, float hi) {
    u32 r;
    asm("v_cvt_pk_bf16_f32 %0, %1, %2" : "=v"(r) : "v"(lo), "v"(hi));
    return r;
}
__device__ __forceinline__ u32 pk_f16(float a, float b) {  // v_cvt_pkrtz_f16_f32
    auto r = __builtin_amdgcn_cvt_pkrtz(a, b);   // __fp16 ext_vector(2)
    u32 out;
    __builtin_memcpy(&out, &r, 4);               // bit-copy, zero cost
    return out;
}
__device__ __forceinline__ h2 as_h2(u32 x) { union { u32 u; h2 h; } v; v.u = x; return v.h; }
__device__ __forceinline__ u32 as_u32h(h2 x) { union { u32 u; h2 h; } v; v.h = x; return v.u; }

// packed {sign(a),sign(b)} as f16 +-1.0
__device__ __forceinline__ u32 sg2(float a, float b) {
    u32 sa = 0x3C00u | ((__float_as_uint(a) >> 16) & 0x8000u);
    u32 sb = 0x3C00u | ((__float_as_uint(b) >> 16) & 0x8000u);
    return sa | (sb << 16);
}

__device__ __forceinline__ int load_idx(const void* ei, int is64, int pos) {
    if (is64) return (int)((const long long*)ei)[pos];
    return ((const int*)ei)[pos];
}

// edge accumulate over one 16B chunk (8 h): t=a+b (pk f16), rabs += dot(|t|,sgn),
// rlin += dot(t, ones). lrelu identity: w*lrelu(x) = (0.505/0.495)*t + sign(w)*|t|
// with t = 0.495*w*x folded into storage.
__device__ __forceinline__ void eacc(uint4 a, uint4 b, const u32* sgn,
                                     float& rlin, float& rabs) {
    const u32* ap = (const u32*)&a;
    const u32* bp = (const u32*)&b;
    #pragma unroll
    for (int k = 0; k < 4; ++k) {
        h2 t = as_h2(ap[k]) + as_h2(bp[k]);           // v_pk_add_f16
        u32 tu = as_u32h(t);
        rabs = __builtin_amdgcn_fdot2(as_h2(tu & 0x7FFF7FFFu), as_h2(sgn[k]),
                                      rabs, false);    // v_dot2_f32_f16
        rlin = __builtin_amdgcn_fdot2(t, as_h2(0x3C003C00u), rlin, false);
    }
}

// ---------------------------------------------------------------------------
// MFMA node projection (round-6 structure; W in registers, z tile in LDS).
// Output is w-folded fp16: pcomb[n][col] = 0.495*W2[col&63]*(proj+bias),
// cols 0..63 = left (src) half, 64..127 = right (dst) half. z loads are
// NON-TEMPORAL (streamed once; don't evict pcomb/W from L2).
// MFMA orientation invariants verified rounds 3-7 (absmax 3.9e-3).
// Block 0 detects int32 vs int64 edge_index into *flag.
// ---------------------------------------------------------------------------
__global__ __launch_bounds__(256) void node_proj_v2(
    const float* __restrict__ z, const float* __restrict__ W1l,
    const float* __restrict__ b1l, const float* __restrict__ W1r,
    const float* __restrict__ b1r, const float* __restrict__ W2,
    const u32* __restrict__ ei_words, int* __restrict__ flag,
    u16* __restrict__ pcomb) {
    __shared__ uint4 zt[64 * 16];   // 16 KB
    __shared__ u32 red;

    const int tid = threadIdx.x;

    if (blockIdx.x == 0) {  // is64 detect: high words of first 2048 entries
        if (tid == 0) red = 0u;
        __syncthreads();
        u32 acc = 0u;
        #pragma unroll
        for (int i = 0; i < 8; ++i)
            acc |= ei_words[(i * 256 + tid) * 2 + 1];
        atomicOr(&red, acc);
        __syncthreads();
        if (tid == 0) *flag = (red == 0u) ? 1 : 0;
    }

    const int wave = tid >> 6, lane = tid & 63;
    const int m = lane & 15, g = lane >> 4;

    // ---- W fragments -> registers (once per block)
    bf16x8 wf[2][4];
    #pragma unroll
    for (int c2 = 0; c2 < 2; ++c2) {
        const int R = (wave << 5) + (c2 << 4) + m;   // R & 15 == m
        const float* wsrc = (R < 64) ? (W1l + R * IN_CH)
                                     : (W1r + (R - 64) * IN_CH);
        #pragma unroll
        for (int kk = 0; kk < 4; ++kk) {
            const int gran = (kk << 2) | g;
            f4 a = ((const f4*)wsrc)[gran * 2];
            f4 b = ((const f4*)wsrc)[gran * 2 + 1];
            uint4 p;
            p.x = cvt_pk_bf(a.x, a.y); p.y = cvt_pk_bf(a.z, a.w);
            p.z = cvt_pk_bf(b.x, b.y); p.w = cvt_pk_bf(b.z, b.w);
            wf[c2][kk] = *(const bf16x8*)&p;
        }
    }

    // bias + fold coefficients for this thread's output columns
    const int colbase = wave << 5;
    f4 bb[2], wq[2];
    #pragma unroll
    for (int c2 = 0; c2 < 2; ++c2) {
        const int col0 = colbase + (c2 << 4) + (g << 2);
        bb[c2] = *(const f4*)((colbase < 64) ? (b1l + col0) : (b1r + col0 - 64));
        f4 wv = *(const f4*)(W2 + (col0 & 63));
        wq[c2].x = 0.495f * wv.x; wq[c2].y = 0.495f * wv.y;
        wq[c2].z = 0.495f * wv.z; wq[c2].w = 0.495f * wv.w;
    }

    const fv4* zp = (const fv4*)z;
    const int ntiles = (N_NODES + 63) / 64;  // 1563
    for (int tile = blockIdx.x; tile < ntiles; tile += NP_GRID) {
        const int base = tile * 64;
        __syncthreads();   // previous tile's readers done -> zt reusable
        #pragma unroll
        for (int i = 0; i < 4; ++i) {
            int gidx = tid + i * 256;
            int row = gidx >> 4, gr = gidx & 15;
            int node = base + row;
            if (node >= N_NODES) node = N_NODES - 1;  // pad reads
            fv4 a = __builtin_nontemporal_load(&zp[node * 32 + gr * 2]);
            fv4 b = __builtin_nontemporal_load(&zp[node * 32 + gr * 2 + 1]);
            uint4 p;
            p.x = cvt_pk_bf(a[0], a[1]); p.y = cvt_pk_bf(a[2], a[3]);
            p.z = cvt_pk_bf(b[0], b[1]); p.w = cvt_pk_bf(b[2], b[3]);
            zt[(row << 4) | (gr ^ (row & 15))] = p;
        }
        __syncthreads();

        f32x4 acc[4][2];
        #pragma unroll
        for (int n4 = 0; n4 < 4; ++n4)
            #pragma unroll
            for (int c2 = 0; c2 < 2; ++c2) acc[n4][c2] = {0.f, 0.f, 0.f, 0.f};

        #pragma unroll
        for (int kk = 0; kk < 4; ++kk) {
            const int gran = (kk << 2) | g;
            bf16x8 zf[4];
            #pragma unroll
            for (int n4 = 0; n4 < 4; ++n4)
                zf[n4] = *(const bf16x8*)&zt[(((n4 << 4) | m) << 4) | (gran ^ m)];
            #pragma unroll
            for (int n4 = 0; n4 < 4; ++n4)
                #pragma unroll
                for (int c2 = 0; c2 < 2; ++c2)
                    acc[n4][c2] = __builtin_amdgcn_mfma_f32_16x16x32_bf16(
                        wf[c2][kk], zf[n4], acc[n4][c2], 0, 0, 0);
        }

        #pragma unroll
        for (int c2 = 0; c2 < 2; ++c2) {
            const int col0 = colbase + (c2 << 4) + (g << 2);
            #pragma unroll
            for (int n4 = 0; n4 < 4; ++n4) {
                int node = base + (n4 << 4) + m;
                if (node < N_NODES) {
                    uint2 v;
                    v.x = pk_f16((acc[n4][c2][0] + bb[c2].x) * wq[c2].x,
                                 (acc[n4][c2][1] + bb[c2].y) * wq[c2].y);
                    v.y = pk_f16((acc[n4][c2][2] + bb[c2].z) * wq[c2].z,
                                 (acc[n4][c2][3] + bb[c2].w) * wq[c2].w);
                    *(uint2*)(pcomb + (size_t)node * 128 + col0) = v;
                }
            }
        }
    }
}

// ---------------------------------------------------------------------------
// Edge kernel: 8 lanes per quad of 4 edges; lane c gathers 16B chunk c of the
// left half (src) + chunk 8+c of the right half (dst). Packed f16 math:
// per 2 h = pk_add + and(abs) + 2x dot2 (vs ~12 VALU before). Index loads and
// out store are non-temporal (read/written once; keep pcomb in L2).
// ---------------------------------------------------------------------------
__global__ __launch_bounds__(256) void edge_quad_kernel(
    const void* __restrict__ ei, const int* __restrict__ flag,
    const u16* __restrict__ pcomb, const float* __restrict__ W2,
    const float* __restrict__ b2, float* __restrict__ out) {
    int t = blockIdx.x * 256 + threadIdx.x;
    int q = t >> 3;
    int c = t & 7;
    if (q >= N_EDGES / 4) return;
    const int is64 = *flag;

    // per-lane packed sign pairs for chunk c (h = 8c..8c+7)
    f4 wa = ((const f4*)W2)[c * 2];
    f4 wb = ((const f4*)W2)[c * 2 + 1];
    u32 sgn[4];
    sgn[0] = sg2(wa.x, wa.y); sgn[1] = sg2(wa.z, wa.w);
    sgn[2] = sg2(wb.x, wb.y); sgn[3] = sg2(wb.z, wb.w);

    int s[4], d[4];
    if (is64) {
        const ll2* p = (const ll2*)ei;
        ll2 p0 = __builtin_nontemporal_load(&p[2 * q]);
        ll2 p1 = __builtin_nontemporal_load(&p[2 * q + 1]);
        ll2 q0 = __builtin_nontemporal_load(&p[N_EDGES / 2 + 2 * q]);
        ll2 q1 = __builtin_nontemporal_load(&p[N_EDGES / 2 + 2 * q + 1]);
        s[0] = (int)p0[0]; s[1] = (int)p0[1]; s[2] = (int)p1[0]; s[3] = (int)p1[1];
        d[0] = (int)q0[0]; d[1] = (int)q0[1]; d[2] = (int)q1[0]; d[3] = (int)q1[1];
    } else {
        const iv4* p = (const iv4*)ei;
        iv4 sp = __builtin_nontemporal_load(&p[q]);
        iv4 dp = __builtin_nontemporal_load(&p[N_EDGES / 4 + q]);
        s[0] = sp[0]; s[1] = sp[1]; s[2] = sp[2]; s[3] = sp[3];
        d[0] = dp[0]; d[1] = dp[1]; d[2] = dp[2]; d[3] = dp[3];
    }
    const uint4* pc4 = (const uint4*)pcomb;
    uint4 a0 = pc4[s[0] * 16 + c],     a1 = pc4[s[1] * 16 + c];
    uint4 a2 = pc4[s[2] * 16 + c],     a3 = pc4[s[3] * 16 + c];
    uint4 e0 = pc4[d[0] * 16 + 8 + c], e1 = pc4[d[1] * 16 + 8 + c];
    uint4 e2 = pc4[d[2] * 16 + 8 + c], e3 = pc4[d[3] * 16 + 8 + c];

    float rl0 = 0.f, ra0 = 0.f, rl1 = 0.f, ra1 = 0.f;
    float rl2 = 0.f, ra2 = 0.f, rl3 = 0.f, ra3 = 0.f;
    eacc(a0, e0, sgn, rl0, ra0);
    eacc(a1, e1, sgn, rl1, ra1);
    eacc(a2, e2, sgn, rl2, ra2);
    eacc(a3, e3, sgn, rl3, ra3);
    // logit partial = (0.505/0.495)*sum(t) + sum(sign*|t|)
    const float K = 1.02020202020202f;
    float r0 = fmaf(rl0, K, ra0);
    float r1 = fmaf(rl1, K, ra1);
    float r2 = fmaf(rl2, K, ra2);
    float r3 = fmaf(rl3, K, ra3);
    #pragma unroll
    for (int off = 4; off; off >>= 1) {
        r0 += __shfl_xor(r0, off, 8);
        r1 += __shfl_xor(r1, off, 8);
        r2 += __shfl_xor(r2, off, 8);
        r3 += __shfl_xor(r3, off, 8);
    }
    if (c == 0) {
        float bbs = b2[0];
        fv4 o;
        o[0] = 1.f / (1.f + __expf(-(r0 + bbs)));
        o[1] = 1.f / (1.f + __expf(-(r1 + bbs)));
        o[2] = 1.f / (1.f + __expf(-(r2 + bbs)));
        o[3] = 1.f / (1.f + __expf(-(r3 + bbs)));
        __builtin_nontemporal_store(o, (fv4*)(out + q * 4));
    }
}

// ---------------------------------------------------------------------------
// Tiny-workspace fallbacks (proven, compute straight from z in fp32)
// ---------------------------------------------------------------------------
__device__ __forceinline__ float lrelu(float x) { return fmaxf(x, 0.01f * x); }

__global__ void detect_idx_kernel(const u32* __restrict__ ei_words,
                                  int* __restrict__ flag) {
    __shared__ u32 red;
    if (threadIdx.x == 0) red = 0u;
    __syncthreads();
    u32 acc = 0u;
    #pragma unroll
    for (int i = 0; i < 8; ++i)
        acc |= ei_words[(i * 256 + threadIdx.x) * 2 + 1];
    atomicOr(&red, acc);
    __syncthreads();
    if (threadIdx.x == 0) *flag = (red == 0u) ? 1 : 0;
}

__global__ __launch_bounds__(256) void edge_fallback_kernel(
    const float* __restrict__ z, const void* __restrict__ ei,
    const int* __restrict__ flag, const float* __restrict__ W1l,
    const float* __restrict__ b1l, const float* __restrict__ W1r,
    const float* __restrict__ b1r, const float* __restrict__ W2,
    const float* __restrict__ b2, float* __restrict__ out) {
    __shared__ f4 Wl4[64 * 32];
    __shared__ f4 Wr4[64 * 32];
    const int tid = threadIdx.x;
    #pragma unroll
    for (int i = 0; i < 8; ++i) {
        int gg = tid + i * 256;
        int h = gg >> 5, v = gg & 31;
        int slot = (h << 5) | (v ^ (h & 7));
        Wl4[slot] = ((const f4*)W1l)[gg];
        Wr4[slot] = ((const f4*)W1r)[gg];
    }
    __syncthreads();
    const int wave = tid >> 6, lane = tid & 63;
    int e = blockIdx.x * 4 + wave;
    if (e >= N_EDGES) return;
    const int is64 = (flag != nullptr) ? *flag : 0;
    int src = load_idx(ei, is64, e);
    int dst = load_idx(ei, is64, N_EDGES + e);
    float accl = 0.f, accr = 0.f;
    #pragma unroll 4
    for (int v = 0; v < 32; ++v) {
        f4 wl = Wl4[(lane << 5) | (v ^ (lane & 7))];
        f4 wr = Wr4[(lane << 5) | (v ^ (lane & 7))];
        f4 zl = ((const f4*)z)[src * 32 + v];
        f4 zr = ((const f4*)z)[dst * 32 + v];
        accl += wl.x * zl.x + wl.y * zl.y + wl.z * zl.z + wl.w * zl.w;
        accr += wr.x * zr.x + wr.y * zr.y + wr.z * zr.z + wr.w * zr.w;
    }
    float h = lrelu(accl + b1l[lane] + accr + b1r[lane]) * W2[lane];
    #pragma unroll
    for (int off = 32; off; off >>= 1) h += __shfl_xor(h, off, 64);
    if (lane == 0) out[e] = 1.f / (1.f + __expf(-(h + b2[0])));
}

extern "C" void kernel_launch(void* const* d_in, const int* in_sizes, int n_in,
                              void* d_out, int out_size, void* d_ws,
                              size_t ws_size, hipStream_t stream) {
    const float* z   = (const float*)d_in[0];
    const void*  ei  = d_in[1];
    const float* W1l = (const float*)d_in[2];
    const float* b1l = (const float*)d_in[3];
    const float* W1r = (const float*)d_in[4];
    const float* b1r = (const float*)d_in[5];
    const float* W2  = (const float*)d_in[6];
    const float* b2  = (const float*)d_in[7];
    float* out = (float*)d_out;

    const size_t pcomb_bytes = (size_t)N_NODES * 128 * sizeof(u16);  // 25.6 MB
    const size_t need = pcomb_bytes + 256;

    if (ws_size >= need) {
        u16* pcomb = (u16*)d_ws;
        int* flag = (int*)((char*)d_ws + pcomb_bytes);
        node_proj_v2<<<NP_GRID, 256, 0, stream>>>(
            z, W1l, b1l, W1r, b1r, W2, (const u32*)ei, flag, pcomb);
        edge_quad_kernel<<<(N_EDGES / 4 * 8 + 255) / 256, 256, 0, stream>>>(
            ei, flag, pcomb, W2, b2, out);
    } else if (ws_size >= 256) {
        int* flag = (int*)d_ws;
        detect_idx_kernel<<<1, 256, 0, stream>>>((const u32*)ei, flag);
        edge_fallback_kernel<<<(N_EDGES + 3) / 4, 256, 0, stream>>>(
            z, ei, flag, W1l, b1l, W1r, b1r, W2, b2, out);
    } else {
        edge_fallback_kernel<<<(N_EDGES + 3) / 4, 256, 0, stream>>>(
            z, ei, nullptr, W1l, b1l, W1r, b1r, W2, b2, out);
    }
}

// Round 10
// 46.036 us; speedup vs baseline: 2.7049x; 1.1919x over previous
//
#include <hip/hip_runtime.h>
#include <math.h>

#define N_NODES 100000
#define N_EDGES 600000
#define IN_CH 128
#define HID 64
#define NEG_SLOPE 0.01f

typedef float4 f4;
typedef unsigned short u16;
typedef unsigned int u32;
typedef __attribute__((ext_vector_type(8))) short bf16x8;   // 8 bf16 (4 VGPRs)
typedef __attribute__((ext_vector_type(4))) float f32x4;    // MFMA acc

__device__ __forceinline__ float lrelu(float x) {
    return fmaxf(x, NEG_SLOPE * x);
}
__device__ __forceinline__ float uasf(u32 w) { return __uint_as_float(w); }

// HW packed conversion: one VALU op for 2 f32 -> packed bf16.
__device__ __forceinline__ u32 cvt_pk(float lo, float hi) {
    u32 r;
    asm("v_cvt_pk_bf16_f32 %0, %1, %2" : "=v"(r) : "v"(lo), "v"(hi));
    return r;
}
// software fallback pack (used only in ws-too-small fallback path)
__device__ __forceinline__ u16 f2bf(float f) {
    u32 x = __float_as_uint(f);
    return (u16)((x + 0x7fffu + ((x >> 16) & 1u)) >> 16);
}

__device__ __forceinline__ int load_idx(const void* ei, int is64, int pos) {
    if (is64) return (int)((const long long*)ei)[pos];
    return ((const int*)ei)[pos];
}

// ---------------------------------------------------------------------------
// MFMA node projection. pcomb[n][0:64] = W1l·z[n]+b1l, [64:128] = W1r·z[n]+b1r
// (bf16). Block = 256 thr (4 waves), tile = 64 nodes × 128 outs, K=128.
// Wave tile = 64 nodes × 32 h-cols (acc[4][2]) -> 24 ds_read_b128/thread.
// LDS XOR swizzle slot = (row<<4) | (gr ^ (row&15)) — conflict-free b128 reads
// (0 bank conflicts measured rounds 2-7).
// Orientation invariants (ref-verified rounds 3-7, absmax 3.9e-3):
//   acc = mfma(W_frag, z_frag, acc); B-frag from z-row (16t+m) -> D col m owns
//   node base+16t+m; A-frag from W-row (R0+m) -> D row 4g+j is h R0+4g+j.
//   Shared K-slot bijection gran=(kk<<2)|g (dot-product permutation-invariant).
// Block 0 additionally detects int32 vs int64 edge_index into *flag.
// [R9 lesson: keep plain (cached) loads — nt hints + f16 fold regressed 7.5us]
// ---------------------------------------------------------------------------
__global__ __launch_bounds__(256) void node_proj_kernel(
    const float* __restrict__ z, const float* __restrict__ W1l,
    const float* __restrict__ b1l, const float* __restrict__ W1r,
    const float* __restrict__ b1r, const u32* __restrict__ ei_words,
    int* __restrict__ flag, u16* __restrict__ pcomb) {
    __shared__ uint4 wt[128 * 16];  // 32 KB
    __shared__ uint4 zt[64 * 16];   // 16 KB
    __shared__ u32 red;

    const int tid = threadIdx.x;

    if (blockIdx.x == 0) {  // is64 detect (high words of first 2048 entries)
        if (tid == 0) red = 0u;
        __syncthreads();
        u32 acc = 0u;
        #pragma unroll
        for (int i = 0; i < 8; ++i)
            acc |= ei_words[(i * 256 + tid) * 2 + 1];
        atomicOr(&red, acc);
        __syncthreads();
        if (tid == 0) *flag = (red == 0u) ? 1 : 0;
    }

    // stage W_comb as bf16, swizzled
    #pragma unroll
    for (int i = 0; i < 8; ++i) {
        int gidx = tid + i * 256;        // row*16 + gr, 0..2047
        int row = gidx >> 4, gr = gidx & 15;
        const float* wsrc = (row < 64) ? (W1l + row * IN_CH)
                                       : (W1r + (row - 64) * IN_CH);
        f4 a = ((const f4*)wsrc)[gr * 2];
        f4 b = ((const f4*)wsrc)[gr * 2 + 1];
        uint4 p;
        p.x = cvt_pk(a.x, a.y); p.y = cvt_pk(a.z, a.w);
        p.z = cvt_pk(b.x, b.y); p.w = cvt_pk(b.z, b.w);
        wt[(row << 4) | (gr ^ (row & 15))] = p;
    }

    // stage z tile (64 nodes), bf16, same swizzle
    const int base = blockIdx.x * 64;
    #pragma unroll
    for (int i = 0; i < 4; ++i) {
        int gidx = tid + i * 256;        // row*16 + gr, 0..1023
        int row = gidx >> 4, gr = gidx & 15;
        int node = base + row;
        if (node >= N_NODES) node = N_NODES - 1;  // pad reads, stores guarded
        f4 a = ((const f4*)z)[node * 32 + gr * 2];
        f4 b = ((const f4*)z)[node * 32 + gr * 2 + 1];
        uint4 p;
        p.x = cvt_pk(a.x, a.y); p.y = cvt_pk(a.z, a.w);
        p.z = cvt_pk(b.x, b.y); p.w = cvt_pk(b.z, b.w);
        zt[(row << 4) | (gr ^ (row & 15))] = p;
    }
    __syncthreads();

    const int wave = tid >> 6, lane = tid & 63;
    const int m = lane & 15, g = lane >> 4;

    f32x4 acc[4][2];
    #pragma unroll
    for (int n4 = 0; n4 < 4; ++n4)
        #pragma unroll
        for (int c2 = 0; c2 < 2; ++c2) acc[n4][c2] = {0.f, 0.f, 0.f, 0.f};

    #pragma unroll
    for (int kk = 0; kk < 4; ++kk) {
        const int gran = (kk << 2) | g;
        bf16x8 zf[4], wf[2];
        #pragma unroll
        for (int n4 = 0; n4 < 4; ++n4)
            zf[n4] = *(const bf16x8*)&zt[(((n4 << 4) | m) << 4) | (gran ^ m)];
        #pragma unroll
        for (int c2 = 0; c2 < 2; ++c2) {
            int R = (wave << 5) + (c2 << 4) + m;   // R & 15 == m
            wf[c2] = *(const bf16x8*)&wt[(R << 4) | (gran ^ m)];
        }
        #pragma unroll
        for (int n4 = 0; n4 < 4; ++n4)
            #pragma unroll
            for (int c2 = 0; c2 < 2; ++c2)
                acc[n4][c2] = __builtin_amdgcn_mfma_f32_16x16x32_bf16(
                    wf[c2], zf[n4], acc[n4][c2], 0, 0, 0);
    }

    // epilogue: bias + cvt_pk pack + 8B stores
    const int colbase = wave << 5;
    #pragma unroll
    for (int c2 = 0; c2 < 2; ++c2) {
        const int col0 = colbase + (c2 << 4) + (g << 2);
        const float* bsrc = (colbase < 64) ? (b1l + col0) : (b1r + col0 - 64);
        f4 bb = *(const f4*)bsrc;
        #pragma unroll
        for (int n4 = 0; n4 < 4; ++n4) {
            int node = base + (n4 << 4) + m;
            if (node < N_NODES) {
                uint2 v;
                v.x = cvt_pk(acc[n4][c2][0] + bb.x, acc[n4][c2][1] + bb.y);
                v.y = cvt_pk(acc[n4][c2][2] + bb.z, acc[n4][c2][3] + bb.w);
                *(uint2*)(pcomb + (size_t)node * 128 + col0) = v;
            }
        }
    }
}

// ---------------------------------------------------------------------------
// Edge kernel: 8 lanes per edge-PAIR slot; each thread handles 2 adjacent
// edges (paired 16B index load, 4 independent gathers in flight, float2 out).
// ---------------------------------------------------------------------------
__device__ __forceinline__ float edot(uint4 a, uint4 b, f4 w0, f4 w1) {
    float s;
    s  = lrelu(uasf(a.x << 16) + uasf(b.x << 16)) * w0.x;
    s += lrelu(uasf(a.x & 0xffff0000u) + uasf(b.x & 0xffff0000u)) * w0.y;
    s += lrelu(uasf(a.y << 16) + uasf(b.y << 16)) * w0.z;
    s += lrelu(uasf(a.y & 0xffff0000u) + uasf(b.y & 0xffff0000u)) * w0.w;
    s += lrelu(uasf(a.z << 16) + uasf(b.z << 16)) * w1.x;
    s += lrelu(uasf(a.z & 0xffff0000u) + uasf(b.z & 0xffff0000u)) * w1.y;
    s += lrelu(uasf(a.w << 16) + uasf(b.w << 16)) * w1.z;
    s += lrelu(uasf(a.w & 0xffff0000u) + uasf(b.w & 0xffff0000u)) * w1.w;
    return s;
}

__global__ __launch_bounds__(256) void edge_kernel(
    const void* __restrict__ ei, const int* __restrict__ flag,
    const u16* __restrict__ pcomb, const float* __restrict__ W2,
    const float* __restrict__ b2, float* __restrict__ out) {
    int t = blockIdx.x * 256 + threadIdx.x;
    int pair = t >> 3;
    int c = t & 7;
    if (pair >= N_EDGES / 2) return;
    const int is64 = *flag;  // uniform
    int s0, s1, d0, d1;
    if (is64) {
        const longlong2* p = (const longlong2*)ei;
        longlong2 sp = p[pair];
        longlong2 dp = p[N_EDGES / 2 + pair];
        s0 = (int)sp.x; s1 = (int)sp.y; d0 = (int)dp.x; d1 = (int)dp.y;
    } else {
        const int2* p = (const int2*)ei;
        int2 sp = p[pair];
        int2 dp = p[N_EDGES / 2 + pair];
        s0 = sp.x; s1 = sp.y; d0 = dp.x; d1 = dp.y;
    }
    const uint4* pc4 = (const uint4*)pcomb;
    uint4 a0 = pc4[s0 * 16 + c];
    uint4 b0 = pc4[d0 * 16 + 8 + c];
    uint4 a1 = pc4[s1 * 16 + c];
    uint4 b1 = pc4[d1 * 16 + 8 + c];
    f4 w0 = ((const f4*)W2)[c * 2];
    f4 w1 = ((const f4*)W2)[c * 2 + 1];
    float r0 = edot(a0, b0, w0, w1);
    float r1 = edot(a1, b1, w0, w1);
    r0 += __shfl_xor(r0, 4, 8);
    r0 += __shfl_xor(r0, 2, 8);
    r0 += __shfl_xor(r0, 1, 8);
    r1 += __shfl_xor(r1, 4, 8);
    r1 += __shfl_xor(r1, 2, 8);
    r1 += __shfl_xor(r1, 1, 8);
    if (c == 0) {
        float bb = b2[0];
        float2 o;
        o.x = 1.f / (1.f + __expf(-(r0 + bb)));
        o.y = 1.f / (1.f + __expf(-(r1 + bb)));
        *(float2*)(out + pair * 2) = o;
    }
}

// ---------------------------------------------------------------------------
// Tiny-workspace fallbacks (proven)
// ---------------------------------------------------------------------------
__global__ void detect_idx_kernel(const u32* __restrict__ ei_words,
                                  int* __restrict__ flag) {
    __shared__ u32 red;
    if (threadIdx.x == 0) red = 0u;
    __syncthreads();
    u32 acc = 0u;
    #pragma unroll
    for (int i = 0; i < 8; ++i)
        acc |= ei_words[(i * 256 + threadIdx.x) * 2 + 1];
    atomicOr(&red, acc);
    __syncthreads();
    if (threadIdx.x == 0) *flag = (red == 0u) ? 1 : 0;
}

__global__ __launch_bounds__(256) void edge_fallback_kernel(
    const float* __restrict__ z, const void* __restrict__ ei,
    const int* __restrict__ flag, const float* __restrict__ W1l,
    const float* __restrict__ b1l, const float* __restrict__ W1r,
    const float* __restrict__ b1r, const float* __restrict__ W2,
    const float* __restrict__ b2, float* __restrict__ out) {
    __shared__ f4 Wl4[64 * 32];
    __shared__ f4 Wr4[64 * 32];
    const int tid = threadIdx.x;
    #pragma unroll
    for (int i = 0; i < 8; ++i) {
        int gg = tid + i * 256;
        int h = gg >> 5, v = gg & 31;
        int slot = (h << 5) | (v ^ (h & 7));
        Wl4[slot] = ((const f4*)W1l)[gg];
        Wr4[slot] = ((const f4*)W1r)[gg];
    }
    __syncthreads();
    const int wave = tid >> 6, lane = tid & 63;
    int e = blockIdx.x * 4 + wave;
    if (e >= N_EDGES) return;
    const int is64 = (flag != nullptr) ? *flag : 0;
    int src = load_idx(ei, is64, e);
    int dst = load_idx(ei, is64, N_EDGES + e);
    float accl = 0.f, accr = 0.f;
    #pragma unroll 4
    for (int v = 0; v < 32; ++v) {
        f4 wl = Wl4[(lane << 5) | (v ^ (lane & 7))];
        f4 wr = Wr4[(lane << 5) | (v ^ (lane & 7))];
        f4 zl = ((const f4*)z)[src * 32 + v];
        f4 zr = ((const f4*)z)[dst * 32 + v];
        accl += wl.x * zl.x + wl.y * zl.y + wl.z * zl.z + wl.w * zl.w;
        accr += wr.x * zr.x + wr.y * zr.y + wr.z * zr.z + wr.w * zr.w;
    }
    float h = lrelu(accl + b1l[lane] + accr + b1r[lane]) * W2[lane];
    #pragma unroll
    for (int off = 32; off; off >>= 1) h += __shfl_xor(h, off, 64);
    if (lane == 0) out[e] = 1.f / (1.f + __expf(-(h + b2[0])));
}

extern "C" void kernel_launch(void* const* d_in, const int* in_sizes, int n_in,
                              void* d_out, int out_size, void* d_ws,
                              size_t ws_size, hipStream_t stream) {
    const float* z   = (const float*)d_in[0];
    const void*  ei  = d_in[1];
    const float* W1l = (const float*)d_in[2];
    const float* b1l = (const float*)d_in[3];
    const float* W1r = (const float*)d_in[4];
    const float* b1r = (const float*)d_in[5];
    const float* W2  = (const float*)d_in[6];
    const float* b2  = (const float*)d_in[7];
    float* out = (float*)d_out;

    const size_t pcomb_bytes = (size_t)N_NODES * 128 * sizeof(u16);  // 25.6 MB
    const size_t need = pcomb_bytes + 256;

    if (ws_size >= need) {
        u16* pcomb = (u16*)d_ws;
        int* flag = (int*)((char*)d_ws + pcomb_bytes);
        node_proj_kernel<<<(N_NODES + 63) / 64, 256, 0, stream>>>(
            z, W1l, b1l, W1r, b1r, (const u32*)ei, flag, pcomb);
        edge_kernel<<<(N_EDGES / 2 * 8 + 255) / 256, 256, 0, stream>>>(
            ei, flag, pcomb, W2, b2, out);
    } else if (ws_size >= 256) {
        int* flag = (int*)d_ws;
        detect_idx_kernel<<<1, 256, 0, stream>>>((const u32*)ei, flag);
        edge_fallback_kernel<<<(N_EDGES + 3) / 4, 256, 0, stream>>>(
            z, ei, flag, W1l, b1l, W1r, b1r, W2, b2, out);
    } else {
        edge_fallback_kernel<<<(N_EDGES + 3) / 4, 256, 0, stream>>>(
            z, ei, nullptr, W1l, b1l, W1r, b1r, W2, b2, out);
    }
}